// Round 9
// baseline (385.824 us; speedup 1.0000x reference)
//
#include <hip/hip_runtime.h>

#define TPB 256
#define BSH 9                   // log2(nodes per bucket)
#define BNODES (1 << BSH)       // 512
#define BMASK (BNODES - 1)
#define SCAT_TPB 1024
#define STILE 16384             // edges per k_scat tile (64 KB stage)
#define EPT 16                  // edges per thread in k_scat (STILE/SCAT_TPB)
#define SORT_TPB 1024
#define CAP 18432               // bucket segment capacity (mean 16384, +16 sigma)

typedef _Float16 half8 __attribute__((ext_vector_type(8)));
typedef _Float16 half2v __attribute__((ext_vector_type(2)));

// ---------------- init: gpos[b] = b*CAP, gsum = 0 ----------------
__global__ void k_init(int* __restrict__ gpos, float* __restrict__ gsum,
                       int nbuck, int gsum_len) {
  int i = blockIdx.x * blockDim.x + threadIdx.x;
  if (i < nbuck) gpos[i] = i * CAP;
  if (i < gsum_len) gsum[i] = 0.0f;
}

// ---------------- tile-sort scatter into segmented buckets ----------------
__global__ void __launch_bounds__(SCAT_TPB)
k_scat(const int* __restrict__ src, const int* __restrict__ dst,
       int* __restrict__ gpos, unsigned* __restrict__ bucketed,
       int E, int nbuck) {
  __shared__ unsigned stage[STILE];   // 64 KB, bucket-sorted tile
  __shared__ int cnt[512];
  __shared__ int runp[512];
  __shared__ int lofs[513];
  __shared__ int base[512];
  __shared__ int wsum[16];
  int t = threadIdx.x;
  int ts = blockIdx.x * STILE;
  int count = min(STILE, E - ts);
  int d[EPT], s[EPT];

  for (int i = t; i < nbuck; i += SCAT_TPB) cnt[i] = 0;
  __syncthreads();
  // pass A: load tile into registers + count
#pragma unroll
  for (int j = 0; j < EPT; ++j) {
    int i = j * SCAT_TPB + t;
    if (i < count) {
      d[j] = dst[ts + i];
      s[j] = src[ts + i];
      atomicAdd(&cnt[d[j] >> BSH], 1);
    }
  }
  __syncthreads();
  // scan + global reservation (one atomic per non-empty bucket)
  {
    int v = (t < nbuck) ? cnt[t] : 0;
    int lane = t & 63, wid = t >> 6;
    int inc = v;
    for (int dd = 1; dd < 64; dd <<= 1) {
      int u = __shfl_up(inc, dd, 64);
      if (lane >= dd) inc += u;
    }
    if (lane == 63) wsum[wid] = inc;
    __syncthreads();
    int woff = 0;
    for (int w = 0; w < wid; ++w) woff += wsum[w];
    int excl = woff + inc - v;
    if (t < nbuck) {
      lofs[t] = excl;
      runp[t] = excl;
      base[t] = v ? atomicAdd(&gpos[t], v) : 0;
    }
    if (t == 0) lofs[nbuck] = count;
  }
  __syncthreads();
  // pass B: place registers into stage (bucket-sorted)
#pragma unroll
  for (int j = 0; j < EPT; ++j) {
    int i = j * SCAT_TPB + t;
    if (i < count) {
      int b = d[j] >> BSH;
      int p = atomicAdd(&runp[b], 1);
      stage[p] = ((unsigned)(d[j] & BMASK) << 18) | (unsigned)s[j];
    }
  }
  __syncthreads();
  // pass C: per-wave bucket-run copy (sequential stage reads / global writes)
  {
    int lane = t & 63, wid = t >> 6;
    for (int b = wid; b < nbuck; b += SCAT_TPB / 64) {
      int s0 = lofs[b], s1 = lofs[b + 1];
      int gb = base[b];
      for (int i = s0 + lane; i < s1; i += 64)
        bucketed[gb + (i - s0)] = stage[i];
    }
  }
}

// ---------------- per-bucket node sort: off/endo, dinv, full-bucket-staged csr ----------------
// 1 count pass + 1 scatter pass (whole bucket staged in 72 KB LDS).
__global__ void __launch_bounds__(SORT_TPB)
k_sortb(const unsigned* __restrict__ bucketed, const int* __restrict__ gpos,
        int* __restrict__ csr, int* __restrict__ off, int* __restrict__ endo,
        float* __restrict__ dinv, int N) {
  int b = blockIdx.x;
  int t = threadIdx.x;
  int n0 = b << BSH;
  int beg = b * CAP;
  int end = gpos[b];
  int total = end - beg;
  __shared__ int cntT[BNODES];
  __shared__ int run[BNODES];        // bucket-relative running positions
  __shared__ int wsum[16];
  __shared__ unsigned stage[CAP];    // 72 KB — whole bucket
  if (t < BNODES) cntT[t] = 0;
  __syncthreads();
  for (int i = beg + t; i < end; i += SORT_TPB) {
    unsigned p = bucketed[i];
    atomicAdd(&cntT[(p >> 18) & BMASK], 1);
  }
  __syncthreads();
  int v = (t < BNODES) ? cntT[t] : 0;
  int lane = t & 63, wid = t >> 6;
  int inc = v;
  for (int d = 1; d < 64; d <<= 1) {
    int u = __shfl_up(inc, d, 64);
    if (lane >= d) inc += u;
  }
  if (lane == 63) wsum[wid] = inc;
  __syncthreads();
  int woff = 0;
  for (int w = 0; w < wid; ++w) woff += wsum[w];
  int excl = woff + inc - v;
  if (t < BNODES) {
    run[t] = excl;
    int n = n0 + t;
    if (n < N) {
      off[n] = beg + excl;
      endo[n] = beg + excl + v;
      dinv[n] = rsqrtf((float)v + 1.0f);
    }
  }
  __syncthreads();
  // single scatter pass: place every edge's src into its node-grouped slot
  for (int i = beg + t; i < end; i += SORT_TPB) {
    unsigned p = bucketed[i];
    int idx = (p >> 18) & BMASK;
    int r = atomicAdd(&run[idx], 1);
    stage[r] = p & 0x3ffffu;
  }
  __syncthreads();
  // stream out coalesced
  for (int i = t; i < total; i += SORT_TPB)
    csr[beg + i] = (int)stage[i];
}

// ---------------- hs1 = fp16( dinv * (x @ W1) ), 8 lanes/node coalesced ----------------
// Lane c2 reads the contiguous 64 B sub-row k in [c2*16, c2*16+16): a wave
// reads 8 rows x 512 B fully coalesced, each x line touched exactly once
// (the old 1-thread/row walk thrashed L1 and re-fetched lines ~4x).
__global__ void k_xw1(const float* __restrict__ x, const float* __restrict__ W1,
                      const float* __restrict__ dinv, _Float16* __restrict__ hs,
                      int n_nodes) {
  int t = blockIdx.x * blockDim.x + threadIdx.x;
  int n = t >> 3, c2 = t & 7;
  if (n >= n_nodes) return;
  const float4* xr = reinterpret_cast<const float4*>(x + (size_t)n * 128 + c2 * 16);
  float s[16];
#pragma unroll
  for (int c = 0; c < 16; ++c) s[c] = 0.0f;
#pragma unroll
  for (int q = 0; q < 4; ++q) {
    float4 xv = xr[q];
    const float* w = W1 + (c2 * 16 + q * 4) * 16;  // W1 is 8 KB, L1-hot
#pragma unroll
    for (int c = 0; c < 16; ++c) s[c] = fmaf(xv.x, w[c], s[c]);
#pragma unroll
    for (int c = 0; c < 16; ++c) s[c] = fmaf(xv.y, w[16 + c], s[c]);
#pragma unroll
    for (int c = 0; c < 16; ++c) s[c] = fmaf(xv.z, w[32 + c], s[c]);
#pragma unroll
    for (int c = 0; c < 16; ++c) s[c] = fmaf(xv.w, w[48 + c], s[c]);
  }
  // 8-lane butterfly: sum partials across the k-split (masks 1,2,4 stay in group)
#pragma unroll
  for (int m = 1; m < 8; m <<= 1) {
#pragma unroll
    for (int c = 0; c < 16; ++c) s[c] += __shfl_xor(s[c], m, 64);
  }
  float dn = dinv[n];
  half2v o;
  o[0] = (_Float16)(dn * s[c2 * 2 + 0]);
  o[1] = (_Float16)(dn * s[c2 * 2 + 1]);
  *reinterpret_cast<half2v*>(hs + (size_t)n * 16 + c2 * 2) = o;
}

// ---------------- 8-lane gather: deep-batched, index-prefetched ----------------
__device__ __forceinline__ void gather2(const _Float16* __restrict__ tab,
                                        const int* __restrict__ csr,
                                        int beg, int end, int c2,
                                        float& a0, float& a1) {
  int i = beg;
  int n16 = (end - beg) >> 4;
  if (n16 > 0) {
    int idx[16];
#pragma unroll
    for (int j = 0; j < 16; ++j) idx[j] = csr[i + j];
    for (int it = 1; it < n16; ++it) {
      half2v f[16];
#pragma unroll
      for (int j = 0; j < 16; ++j)
        f[j] = *reinterpret_cast<const half2v*>(tab + (size_t)idx[j] * 16 + c2 * 2);
      // prefetch next batch of indices while table loads are in flight
#pragma unroll
      for (int j = 0; j < 16; ++j) idx[j] = csr[i + 16 + j];
#pragma unroll
      for (int j = 0; j < 16; ++j) { a0 += (float)f[j][0]; a1 += (float)f[j][1]; }
      i += 16;
    }
    // drain the last prefetched batch
    half2v f[16];
#pragma unroll
    for (int j = 0; j < 16; ++j)
      f[j] = *reinterpret_cast<const half2v*>(tab + (size_t)idx[j] * 16 + c2 * 2);
#pragma unroll
    for (int j = 0; j < 16; ++j) { a0 += (float)f[j][0]; a1 += (float)f[j][1]; }
    i += 16;
  }
  if (i + 8 <= end) {
    int idx8[8];
    half2v f[8];
#pragma unroll
    for (int j = 0; j < 8; ++j) idx8[j] = csr[i + j];
#pragma unroll
    for (int j = 0; j < 8; ++j)
      f[j] = *reinterpret_cast<const half2v*>(tab + (size_t)idx8[j] * 16 + c2 * 2);
#pragma unroll
    for (int j = 0; j < 8; ++j) { a0 += (float)f[j][0]; a1 += (float)f[j][1]; }
    i += 8;
  }
  for (; i < end; ++i) {
    int idx = csr[i];
    half2v f = *reinterpret_cast<const half2v*>(tab + (size_t)idx * 16 + c2 * 2);
    a0 += (float)f[0];
    a1 += (float)f[1];
  }
}

// ---------------- gather conv1 + relu + W2 transform (8 lanes/node) ----------------
__global__ void k_gc1(const _Float16* __restrict__ hs1, const int* __restrict__ off,
                      const int* __restrict__ endo, const int* __restrict__ csr,
                      const float* __restrict__ dinv, const float* __restrict__ b1,
                      const float* __restrict__ W2, _Float16* __restrict__ hs2, int N) {
  int t = blockIdx.x * blockDim.x + threadIdx.x;
  int n = t >> 3, c2 = t & 7;
  if (n >= N) return;
  half2v selfr = *reinterpret_cast<const half2v*>(hs1 + (size_t)n * 16 + c2 * 2);
  float a0 = (float)selfr[0], a1 = (float)selfr[1];
  gather2(hs1, csr, off[n], endo[n], c2, a0, a1);
  float dn = dinv[n];
  float h1a = fmaxf(fmaf(dn, a0, b1[c2 * 2 + 0]), 0.0f);
  float h1b = fmaxf(fmaf(dn, a1, b1[c2 * 2 + 1]), 0.0f);
  float oa = 0.0f, ob = 0.0f;
#pragma unroll
  for (int j = 0; j < 8; ++j) {
    float hk0 = __shfl(h1a, j, 8);  // h1[2j]
    float hk1 = __shfl(h1b, j, 8);  // h1[2j+1]
    oa = fmaf(hk0, W2[(2 * j) * 16 + c2 * 2 + 0], oa);
    ob = fmaf(hk0, W2[(2 * j) * 16 + c2 * 2 + 1], ob);
    oa = fmaf(hk1, W2[(2 * j + 1) * 16 + c2 * 2 + 0], oa);
    ob = fmaf(hk1, W2[(2 * j + 1) * 16 + c2 * 2 + 1], ob);
  }
  half2v outv;
  outv[0] = (_Float16)(dn * oa);
  outv[1] = (_Float16)(dn * ob);
  *reinterpret_cast<half2v*>(hs2 + (size_t)n * 16 + c2 * 2) = outv;
}

// ---------------- gather conv2 + bias + pool accumulate (8 lanes/node) ----------------
__global__ void k_gc2(const _Float16* __restrict__ hs2, const int* __restrict__ off,
                      const int* __restrict__ endo, const int* __restrict__ csr,
                      const float* __restrict__ dinv, const float* __restrict__ b2,
                      const int* __restrict__ batch, float* __restrict__ gsum, int N) {
  int t = threadIdx.x;
  int n = blockIdx.x * 32 + (t >> 3);
  int c2 = t & 7;
  float v0 = 0.0f, v1 = 0.0f;
  int g = 0;
  if (n < N) {
    half2v selfr = *reinterpret_cast<const half2v*>(hs2 + (size_t)n * 16 + c2 * 2);
    float a0 = (float)selfr[0], a1 = (float)selfr[1];
    gather2(hs2, csr, off[n], endo[n], c2, a0, a1);
    float dn = dinv[n];
    v0 = fmaf(dn, a0, b2[c2 * 2 + 0]);
    v1 = fmaf(dn, a1, b2[c2 * 2 + 1]);
    g = batch[n];
  }
  // block covers 32 consecutive nodes; batch is sorted -> usually one graph
  __shared__ float2 red[256];
  __shared__ int sg[2];
  int nfirst = blockIdx.x * 32;
  int nlast = min(nfirst + 31, N - 1);
  if (t == 0) sg[0] = batch[nfirst];
  if (t == 255) sg[1] = batch[nlast];
  __syncthreads();
  bool uniform = (sg[0] == sg[1]);
  if (uniform) {
    red[t] = make_float2(v0, v1);
    __syncthreads();
#pragma unroll
    for (int s2 = 16; s2 > 0; s2 >>= 1) {
      if ((t >> 3) < s2) {
        float2 a = red[t], b = red[t + s2 * 8];
        red[t] = make_float2(a.x + b.x, a.y + b.y);
      }
      __syncthreads();
    }
    if (t < 8) {
      float2 r = red[t];
      unsafeAtomicAdd(&gsum[(size_t)sg[0] * 16 + t * 2 + 0], r.x);
      unsafeAtomicAdd(&gsum[(size_t)sg[0] * 16 + t * 2 + 1], r.y);
    }
  } else if (n < N) {
    unsafeAtomicAdd(&gsum[(size_t)g * 16 + c2 * 2 + 0], v0);
    unsafeAtomicAdd(&gsum[(size_t)g * 16 + c2 * 2 + 1], v1);
  }
}

// ---------------- mean + FC head ----------------
__device__ __forceinline__ int lbound(const int* a, int n, int key) {
  int lo = 0, hi = n;
  while (lo < hi) {
    int mid = (lo + hi) >> 1;
    if (a[mid] < key) lo = mid + 1; else hi = mid;
  }
  return lo;
}

__global__ void k_final(const float* __restrict__ gsum, const int* __restrict__ batch,
                        const float* __restrict__ fcW, const float* __restrict__ fcb,
                        float* __restrict__ out, int n_nodes, int num_graphs) {
  int g = blockIdx.x * blockDim.x + threadIdx.x;
  if (g >= num_graphs) return;
  int lo = lbound(batch, n_nodes, g);
  int hi = lbound(batch, n_nodes, g + 1);
  float cnt = (float)(hi - lo);
  float inv = 1.0f / fmaxf(cnt, 1.0f);
  float gv[16];
#pragma unroll
  for (int c = 0; c < 16; ++c) gv[c] = gsum[(size_t)g * 16 + c] * inv;
  float o[16];
#pragma unroll
  for (int c = 0; c < 16; ++c) o[c] = fcb[c];
#pragma unroll
  for (int k = 0; k < 16; ++k) {
    float gk = gv[k];
    const float* w = fcW + k * 16;
#pragma unroll
    for (int c = 0; c < 16; ++c) o[c] = fmaf(gk, w[c], o[c]);
  }
#pragma unroll
  for (int c = 0; c < 16; ++c) out[(size_t)g * 16 + c] = o[c];
}

extern "C" void kernel_launch(void* const* d_in, const int* in_sizes, int n_in,
                              void* d_out, int out_size, void* d_ws, size_t ws_size,
                              hipStream_t stream) {
  const float* x   = (const float*)d_in[0];
  const float* W1  = (const float*)d_in[1];
  const float* b1  = (const float*)d_in[2];
  const float* W2  = (const float*)d_in[3];
  const float* b2  = (const float*)d_in[4];
  const float* fcW = (const float*)d_in[5];
  const float* fcb = (const float*)d_in[6];
  const int* ei    = (const int*)d_in[7];
  const int* batch = (const int*)d_in[8];

  const int IN_CH = 128, HID = 16, NCLS = 16;
  int n_nodes = in_sizes[0] / IN_CH;       // 200000
  int E = in_sizes[7] / 2;                 // 6400000
  int num_graphs = out_size / NCLS;        // 512
  const int* src = ei;
  const int* dst = ei + E;
  int nbuck = (n_nodes + BNODES - 1) >> BSH;  // 391 (<= 512 assumed)
  size_t seg_elems = (size_t)nbuck * CAP;     // segmented capacity

  // workspace: region aliases {bucketed} then {H1, H2}; csr separate.
  char* ws = (char*)d_ws;
  size_t h_bytes = sizeof(_Float16) * (size_t)n_nodes * 16;  // 6.4 MB each
  size_t region_bytes = 2 * h_bytes;
  if (sizeof(unsigned) * seg_elems > region_bytes)
    region_bytes = sizeof(unsigned) * seg_elems;
  unsigned* bucketed = (unsigned*)ws;
  _Float16* H1  = (_Float16*)ws;
  _Float16* H2  = (_Float16*)(ws + h_bytes);
  ws += region_bytes;
  int*   csr  = (int*)ws;   ws += sizeof(int) * seg_elems;
  int*   off  = (int*)ws;   ws += sizeof(int) * ((size_t)n_nodes + 64);
  int*   endo = (int*)ws;   ws += sizeof(int) * ((size_t)n_nodes + 64);
  float* dinv = (float*)ws; ws += sizeof(float) * (size_t)n_nodes;
  int*   gpos = (int*)ws;   ws += sizeof(int) * 1056;
  float* gsum = (float*)ws;

  int gg  = (num_graphs + TPB - 1) / TPB;
  int gnc = ((n_nodes * 8) + TPB - 1) / TPB;   // 8 lanes/node kernels
  int gb  = (n_nodes + 31) / 32;               // k_gc2: 32 nodes/block
  int gs  = (E + STILE - 1) / STILE;           // tiles for k_scat
  int gi  = ((nbuck > num_graphs * HID ? nbuck : num_graphs * HID) + TPB - 1) / TPB;

  k_init <<<gi, TPB, 0, stream>>>(gpos, gsum, nbuck, num_graphs * HID);
  k_scat <<<gs, SCAT_TPB, 0, stream>>>(src, dst, gpos, bucketed, E, nbuck);
  k_sortb<<<nbuck, SORT_TPB, 0, stream>>>(bucketed, gpos, csr, off, endo,
                                          dinv, n_nodes);
  k_xw1  <<<gnc, TPB, 0, stream>>>(x, W1, dinv, H1, n_nodes);
  k_gc1  <<<gnc, TPB, 0, stream>>>(H1, off, endo, csr, dinv, b1, W2, H2, n_nodes);
  k_gc2  <<<gb, TPB, 0, stream>>>(H2, off, endo, csr, dinv, b2, batch, gsum, n_nodes);
  k_final<<<gg, TPB, 0, stream>>>(gsum, batch, fcW, fcb, (float*)d_out,
                                  n_nodes, num_graphs);
}

// Round 10
// 385.204 us; speedup vs baseline: 1.0016x; 1.0016x over previous
//
#include <hip/hip_runtime.h>

#define TPB 256
#define BSH 9                   // log2(nodes per bucket)
#define BNODES (1 << BSH)       // 512
#define BMASK (BNODES - 1)
#define SCAT_TPB 1024
#define STILE 16384             // edges per k_scat tile (64 KB stage)
#define EPT 16                  // edges per thread in k_scat (STILE/SCAT_TPB)
#define SORT_TPB 1024
#define CAP 18432               // bucket segment capacity (mean 16384, +16 sigma)

typedef _Float16 half8 __attribute__((ext_vector_type(8)));
typedef _Float16 half2v __attribute__((ext_vector_type(2)));

// ---------------- init: gpos[b] = b*CAP, gsum = 0 ----------------
__global__ void k_init(int* __restrict__ gpos, float* __restrict__ gsum,
                       int nbuck, int gsum_len) {
  int i = blockIdx.x * blockDim.x + threadIdx.x;
  if (i < nbuck) gpos[i] = i * CAP;
  if (i < gsum_len) gsum[i] = 0.0f;
}

// ---------------- tile-sort scatter into segmented buckets ----------------
__global__ void __launch_bounds__(SCAT_TPB)
k_scat(const int* __restrict__ src, const int* __restrict__ dst,
       int* __restrict__ gpos, unsigned* __restrict__ bucketed,
       int E, int nbuck) {
  __shared__ unsigned stage[STILE];   // 64 KB, bucket-sorted tile
  __shared__ int cnt[512];
  __shared__ int runp[512];
  __shared__ int lofs[513];
  __shared__ int base[512];
  __shared__ int wsum[16];
  int t = threadIdx.x;
  int ts = blockIdx.x * STILE;
  int count = min(STILE, E - ts);
  int d[EPT], s[EPT];

  for (int i = t; i < nbuck; i += SCAT_TPB) cnt[i] = 0;
  __syncthreads();
  // pass A: load tile into registers + count
#pragma unroll
  for (int j = 0; j < EPT; ++j) {
    int i = j * SCAT_TPB + t;
    if (i < count) {
      d[j] = dst[ts + i];
      s[j] = src[ts + i];
      atomicAdd(&cnt[d[j] >> BSH], 1);
    }
  }
  __syncthreads();
  // scan + global reservation (one atomic per non-empty bucket)
  {
    int v = (t < nbuck) ? cnt[t] : 0;
    int lane = t & 63, wid = t >> 6;
    int inc = v;
    for (int dd = 1; dd < 64; dd <<= 1) {
      int u = __shfl_up(inc, dd, 64);
      if (lane >= dd) inc += u;
    }
    if (lane == 63) wsum[wid] = inc;
    __syncthreads();
    int woff = 0;
    for (int w = 0; w < wid; ++w) woff += wsum[w];
    int excl = woff + inc - v;
    if (t < nbuck) {
      lofs[t] = excl;
      runp[t] = excl;
      base[t] = v ? atomicAdd(&gpos[t], v) : 0;
    }
    if (t == 0) lofs[nbuck] = count;
  }
  __syncthreads();
  // pass B: place registers into stage (bucket-sorted)
#pragma unroll
  for (int j = 0; j < EPT; ++j) {
    int i = j * SCAT_TPB + t;
    if (i < count) {
      int b = d[j] >> BSH;
      int p = atomicAdd(&runp[b], 1);
      stage[p] = ((unsigned)(d[j] & BMASK) << 18) | (unsigned)s[j];
    }
  }
  __syncthreads();
  // pass C: per-wave bucket-run copy (sequential stage reads / global writes)
  {
    int lane = t & 63, wid = t >> 6;
    for (int b = wid; b < nbuck; b += SCAT_TPB / 64) {
      int s0 = lofs[b], s1 = lofs[b + 1];
      int gb = base[b];
      for (int i = s0 + lane; i < s1; i += 64)
        bucketed[gb + (i - s0)] = stage[i];
    }
  }
}

// ---------------- per-bucket node sort: off/endo, dinv, full-bucket-staged csr ----------------
// 1 count pass + 1 scatter pass (whole bucket staged in 72 KB LDS).
__global__ void __launch_bounds__(SORT_TPB)
k_sortb(const unsigned* __restrict__ bucketed, const int* __restrict__ gpos,
        int* __restrict__ csr, int* __restrict__ off, int* __restrict__ endo,
        float* __restrict__ dinv, int N) {
  int b = blockIdx.x;
  int t = threadIdx.x;
  int n0 = b << BSH;
  int beg = b * CAP;
  int end = gpos[b];
  int total = end - beg;
  __shared__ int cntT[BNODES];
  __shared__ int run[BNODES];        // bucket-relative running positions
  __shared__ int wsum[16];
  __shared__ unsigned stage[CAP];    // 72 KB — whole bucket
  if (t < BNODES) cntT[t] = 0;
  __syncthreads();
  for (int i = beg + t; i < end; i += SORT_TPB) {
    unsigned p = bucketed[i];
    atomicAdd(&cntT[(p >> 18) & BMASK], 1);
  }
  __syncthreads();
  int v = (t < BNODES) ? cntT[t] : 0;
  int lane = t & 63, wid = t >> 6;
  int inc = v;
  for (int d = 1; d < 64; d <<= 1) {
    int u = __shfl_up(inc, d, 64);
    if (lane >= d) inc += u;
  }
  if (lane == 63) wsum[wid] = inc;
  __syncthreads();
  int woff = 0;
  for (int w = 0; w < wid; ++w) woff += wsum[w];
  int excl = woff + inc - v;
  if (t < BNODES) {
    run[t] = excl;
    int n = n0 + t;
    if (n < N) {
      off[n] = beg + excl;
      endo[n] = beg + excl + v;
      dinv[n] = rsqrtf((float)v + 1.0f);
    }
  }
  __syncthreads();
  // single scatter pass: place every edge's src into its node-grouped slot
  for (int i = beg + t; i < end; i += SORT_TPB) {
    unsigned p = bucketed[i];
    int idx = (p >> 18) & BMASK;
    int r = atomicAdd(&run[idx], 1);
    stage[r] = p & 0x3ffffu;
  }
  __syncthreads();
  // stream out coalesced
  for (int i = t; i < total; i += SORT_TPB)
    csr[beg + i] = (int)stage[i];
}

// ---------------- hs1 = fp16( dinv * (x @ W1) ), 8 lanes/node coalesced ----------------
// Lane c2 reads the contiguous 64 B sub-row k in [c2*16, c2*16+16): a wave reads
// 8 rows x 512 B fully coalesced. Partial sums are combined with a DISTRIBUTED
// reducing exchange (keep/send halves selected by static-index ternaries ->
// v_cndmask, NO runtime array indexing -> stays in registers; rule #20).
// Lane c2 ends holding channels 2*c2 and 2*c2+1.
__global__ void k_xw1(const float* __restrict__ x, const float* __restrict__ W1,
                      const float* __restrict__ dinv, _Float16* __restrict__ hs,
                      int n_nodes) {
  int t = blockIdx.x * blockDim.x + threadIdx.x;
  int n = t >> 3, c2 = t & 7;
  if (n >= n_nodes) return;
  const float4* xr = reinterpret_cast<const float4*>(x + (size_t)n * 128 + c2 * 16);
  float s[16];
#pragma unroll
  for (int c = 0; c < 16; ++c) s[c] = 0.0f;
#pragma unroll
  for (int q = 0; q < 4; ++q) {
    float4 xv = xr[q];
    const float* w = W1 + (c2 * 16 + q * 4) * 16;  // W1 is 8 KB, L1-hot
#pragma unroll
    for (int c = 0; c < 16; ++c) s[c] = fmaf(xv.x, w[c], s[c]);
#pragma unroll
    for (int c = 0; c < 16; ++c) s[c] = fmaf(xv.y, w[16 + c], s[c]);
#pragma unroll
    for (int c = 0; c < 16; ++c) s[c] = fmaf(xv.z, w[32 + c], s[c]);
#pragma unroll
    for (int c = 0; c < 16; ++c) s[c] = fmaf(xv.w, w[48 + c], s[c]);
  }
  // round 1 (partner lane^4): keep my 8 channels, send the other 8
  bool h4 = (c2 & 4) != 0;
  float u[8];
#pragma unroll
  for (int c = 0; c < 8; ++c) {
    float keep = h4 ? s[c + 8] : s[c];
    float send = h4 ? s[c] : s[c + 8];
    u[c] = keep + __shfl_xor(send, 4, 64);
  }
  // round 2 (partner lane^2): 8 -> 4
  bool h2 = (c2 & 2) != 0;
  float v4[4];
#pragma unroll
  for (int c = 0; c < 4; ++c) {
    float keep = h2 ? u[c + 4] : u[c];
    float send = h2 ? u[c] : u[c + 4];
    v4[c] = keep + __shfl_xor(send, 2, 64);
  }
  // round 3 (partner lane^1): 4 -> 2
  bool h1 = (c2 & 1) != 0;
  float k0 = h1 ? v4[2] : v4[0];
  float s0 = h1 ? v4[0] : v4[2];
  float k1 = h1 ? v4[3] : v4[1];
  float s1 = h1 ? v4[1] : v4[3];
  float r0 = k0 + __shfl_xor(s0, 1, 64);
  float r1 = k1 + __shfl_xor(s1, 1, 64);
  float dn = dinv[n];
  half2v o;
  o[0] = (_Float16)(dn * r0);
  o[1] = (_Float16)(dn * r1);
  *reinterpret_cast<half2v*>(hs + (size_t)n * 16 + c2 * 2) = o;
}

// ---------------- 8-lane gather: deep-batched, index-prefetched ----------------
__device__ __forceinline__ void gather2(const _Float16* __restrict__ tab,
                                        const int* __restrict__ csr,
                                        int beg, int end, int c2,
                                        float& a0, float& a1) {
  int i = beg;
  int n16 = (end - beg) >> 4;
  if (n16 > 0) {
    int idx[16];
#pragma unroll
    for (int j = 0; j < 16; ++j) idx[j] = csr[i + j];
    for (int it = 1; it < n16; ++it) {
      half2v f[16];
#pragma unroll
      for (int j = 0; j < 16; ++j)
        f[j] = *reinterpret_cast<const half2v*>(tab + (size_t)idx[j] * 16 + c2 * 2);
      // prefetch next batch of indices while table loads are in flight
#pragma unroll
      for (int j = 0; j < 16; ++j) idx[j] = csr[i + 16 + j];
#pragma unroll
      for (int j = 0; j < 16; ++j) { a0 += (float)f[j][0]; a1 += (float)f[j][1]; }
      i += 16;
    }
    // drain the last prefetched batch
    half2v f[16];
#pragma unroll
    for (int j = 0; j < 16; ++j)
      f[j] = *reinterpret_cast<const half2v*>(tab + (size_t)idx[j] * 16 + c2 * 2);
#pragma unroll
    for (int j = 0; j < 16; ++j) { a0 += (float)f[j][0]; a1 += (float)f[j][1]; }
    i += 16;
  }
  if (i + 8 <= end) {
    int idx8[8];
    half2v f[8];
#pragma unroll
    for (int j = 0; j < 8; ++j) idx8[j] = csr[i + j];
#pragma unroll
    for (int j = 0; j < 8; ++j)
      f[j] = *reinterpret_cast<const half2v*>(tab + (size_t)idx8[j] * 16 + c2 * 2);
#pragma unroll
    for (int j = 0; j < 8; ++j) { a0 += (float)f[j][0]; a1 += (float)f[j][1]; }
    i += 8;
  }
  for (; i < end; ++i) {
    int idx = csr[i];
    half2v f = *reinterpret_cast<const half2v*>(tab + (size_t)idx * 16 + c2 * 2);
    a0 += (float)f[0];
    a1 += (float)f[1];
  }
}

// ---------------- gather conv1 + relu + W2 transform (8 lanes/node) ----------------
__global__ void k_gc1(const _Float16* __restrict__ hs1, const int* __restrict__ off,
                      const int* __restrict__ endo, const int* __restrict__ csr,
                      const float* __restrict__ dinv, const float* __restrict__ b1,
                      const float* __restrict__ W2, _Float16* __restrict__ hs2, int N) {
  int t = blockIdx.x * blockDim.x + threadIdx.x;
  int n = t >> 3, c2 = t & 7;
  if (n >= N) return;
  half2v selfr = *reinterpret_cast<const half2v*>(hs1 + (size_t)n * 16 + c2 * 2);
  float a0 = (float)selfr[0], a1 = (float)selfr[1];
  gather2(hs1, csr, off[n], endo[n], c2, a0, a1);
  float dn = dinv[n];
  float h1a = fmaxf(fmaf(dn, a0, b1[c2 * 2 + 0]), 0.0f);
  float h1b = fmaxf(fmaf(dn, a1, b1[c2 * 2 + 1]), 0.0f);
  float oa = 0.0f, ob = 0.0f;
#pragma unroll
  for (int j = 0; j < 8; ++j) {
    float hk0 = __shfl(h1a, j, 8);  // h1[2j]
    float hk1 = __shfl(h1b, j, 8);  // h1[2j+1]
    oa = fmaf(hk0, W2[(2 * j) * 16 + c2 * 2 + 0], oa);
    ob = fmaf(hk0, W2[(2 * j) * 16 + c2 * 2 + 1], ob);
    oa = fmaf(hk1, W2[(2 * j + 1) * 16 + c2 * 2 + 0], oa);
    ob = fmaf(hk1, W2[(2 * j + 1) * 16 + c2 * 2 + 1], ob);
  }
  half2v outv;
  outv[0] = (_Float16)(dn * oa);
  outv[1] = (_Float16)(dn * ob);
  *reinterpret_cast<half2v*>(hs2 + (size_t)n * 16 + c2 * 2) = outv;
}

// ---------------- gather conv2 + bias + pool accumulate (8 lanes/node) ----------------
__global__ void k_gc2(const _Float16* __restrict__ hs2, const int* __restrict__ off,
                      const int* __restrict__ endo, const int* __restrict__ csr,
                      const float* __restrict__ dinv, const float* __restrict__ b2,
                      const int* __restrict__ batch, float* __restrict__ gsum, int N) {
  int t = threadIdx.x;
  int n = blockIdx.x * 32 + (t >> 3);
  int c2 = t & 7;
  float v0 = 0.0f, v1 = 0.0f;
  int g = 0;
  if (n < N) {
    half2v selfr = *reinterpret_cast<const half2v*>(hs2 + (size_t)n * 16 + c2 * 2);
    float a0 = (float)selfr[0], a1 = (float)selfr[1];
    gather2(hs2, csr, off[n], endo[n], c2, a0, a1);
    float dn = dinv[n];
    v0 = fmaf(dn, a0, b2[c2 * 2 + 0]);
    v1 = fmaf(dn, a1, b2[c2 * 2 + 1]);
    g = batch[n];
  }
  // block covers 32 consecutive nodes; batch is sorted -> usually one graph
  __shared__ float2 red[256];
  __shared__ int sg[2];
  int nfirst = blockIdx.x * 32;
  int nlast = min(nfirst + 31, N - 1);
  if (t == 0) sg[0] = batch[nfirst];
  if (t == 255) sg[1] = batch[nlast];
  __syncthreads();
  bool uniform = (sg[0] == sg[1]);
  if (uniform) {
    red[t] = make_float2(v0, v1);
    __syncthreads();
#pragma unroll
    for (int s2 = 16; s2 > 0; s2 >>= 1) {
      if ((t >> 3) < s2) {
        float2 a = red[t], b = red[t + s2 * 8];
        red[t] = make_float2(a.x + b.x, a.y + b.y);
      }
      __syncthreads();
    }
    if (t < 8) {
      float2 r = red[t];
      unsafeAtomicAdd(&gsum[(size_t)sg[0] * 16 + t * 2 + 0], r.x);
      unsafeAtomicAdd(&gsum[(size_t)sg[0] * 16 + t * 2 + 1], r.y);
    }
  } else if (n < N) {
    unsafeAtomicAdd(&gsum[(size_t)g * 16 + c2 * 2 + 0], v0);
    unsafeAtomicAdd(&gsum[(size_t)g * 16 + c2 * 2 + 1], v1);
  }
}

// ---------------- mean + FC head ----------------
__device__ __forceinline__ int lbound(const int* a, int n, int key) {
  int lo = 0, hi = n;
  while (lo < hi) {
    int mid = (lo + hi) >> 1;
    if (a[mid] < key) lo = mid + 1; else hi = mid;
  }
  return lo;
}

__global__ void k_final(const float* __restrict__ gsum, const int* __restrict__ batch,
                        const float* __restrict__ fcW, const float* __restrict__ fcb,
                        float* __restrict__ out, int n_nodes, int num_graphs) {
  int g = blockIdx.x * blockDim.x + threadIdx.x;
  if (g >= num_graphs) return;
  int lo = lbound(batch, n_nodes, g);
  int hi = lbound(batch, n_nodes, g + 1);
  float cnt = (float)(hi - lo);
  float inv = 1.0f / fmaxf(cnt, 1.0f);
  float gv[16];
#pragma unroll
  for (int c = 0; c < 16; ++c) gv[c] = gsum[(size_t)g * 16 + c] * inv;
  float o[16];
#pragma unroll
  for (int c = 0; c < 16; ++c) o[c] = fcb[c];
#pragma unroll
  for (int k = 0; k < 16; ++k) {
    float gk = gv[k];
    const float* w = fcW + k * 16;
#pragma unroll
    for (int c = 0; c < 16; ++c) o[c] = fmaf(gk, w[c], o[c]);
  }
#pragma unroll
  for (int c = 0; c < 16; ++c) out[(size_t)g * 16 + c] = o[c];
}

extern "C" void kernel_launch(void* const* d_in, const int* in_sizes, int n_in,
                              void* d_out, int out_size, void* d_ws, size_t ws_size,
                              hipStream_t stream) {
  const float* x   = (const float*)d_in[0];
  const float* W1  = (const float*)d_in[1];
  const float* b1  = (const float*)d_in[2];
  const float* W2  = (const float*)d_in[3];
  const float* b2  = (const float*)d_in[4];
  const float* fcW = (const float*)d_in[5];
  const float* fcb = (const float*)d_in[6];
  const int* ei    = (const int*)d_in[7];
  const int* batch = (const int*)d_in[8];

  const int IN_CH = 128, HID = 16, NCLS = 16;
  int n_nodes = in_sizes[0] / IN_CH;       // 200000
  int E = in_sizes[7] / 2;                 // 6400000
  int num_graphs = out_size / NCLS;        // 512
  const int* src = ei;
  const int* dst = ei + E;
  int nbuck = (n_nodes + BNODES - 1) >> BSH;  // 391 (<= 512 assumed)
  size_t seg_elems = (size_t)nbuck * CAP;     // segmented capacity

  // workspace: region aliases {bucketed} then {H1, H2}; csr separate.
  char* ws = (char*)d_ws;
  size_t h_bytes = sizeof(_Float16) * (size_t)n_nodes * 16;  // 6.4 MB each
  size_t region_bytes = 2 * h_bytes;
  if (sizeof(unsigned) * seg_elems > region_bytes)
    region_bytes = sizeof(unsigned) * seg_elems;
  unsigned* bucketed = (unsigned*)ws;
  _Float16* H1  = (_Float16*)ws;
  _Float16* H2  = (_Float16*)(ws + h_bytes);
  ws += region_bytes;
  int*   csr  = (int*)ws;   ws += sizeof(int) * seg_elems;
  int*   off  = (int*)ws;   ws += sizeof(int) * ((size_t)n_nodes + 64);
  int*   endo = (int*)ws;   ws += sizeof(int) * ((size_t)n_nodes + 64);
  float* dinv = (float*)ws; ws += sizeof(float) * (size_t)n_nodes;
  int*   gpos = (int*)ws;   ws += sizeof(int) * 1056;
  float* gsum = (float*)ws;

  int gg  = (num_graphs + TPB - 1) / TPB;
  int gnc = ((n_nodes * 8) + TPB - 1) / TPB;   // 8 lanes/node kernels
  int gb  = (n_nodes + 31) / 32;               // k_gc2: 32 nodes/block
  int gs  = (E + STILE - 1) / STILE;           // tiles for k_scat
  int gi  = ((nbuck > num_graphs * HID ? nbuck : num_graphs * HID) + TPB - 1) / TPB;

  k_init <<<gi, TPB, 0, stream>>>(gpos, gsum, nbuck, num_graphs * HID);
  k_scat <<<gs, SCAT_TPB, 0, stream>>>(src, dst, gpos, bucketed, E, nbuck);
  k_sortb<<<nbuck, SORT_TPB, 0, stream>>>(bucketed, gpos, csr, off, endo,
                                          dinv, n_nodes);
  k_xw1  <<<gnc, TPB, 0, stream>>>(x, W1, dinv, H1, n_nodes);
  k_gc1  <<<gnc, TPB, 0, stream>>>(H1, off, endo, csr, dinv, b1, W2, H2, n_nodes);
  k_gc2  <<<gb, TPB, 0, stream>>>(H2, off, endo, csr, dinv, b2, batch, gsum, n_nodes);
  k_final<<<gg, TPB, 0, stream>>>(gsum, batch, fcW, fcb, (float*)d_out,
                                  n_nodes, num_graphs);
}

// Round 11
// 231.673 us; speedup vs baseline: 1.6654x; 1.6627x over previous
//
#include <hip/hip_runtime.h>

#define TPB 256
#define BSH 9                   // log2(nodes per bucket)
#define BNODES (1 << BSH)       // 512
#define BMASK (BNODES - 1)
#define SCAT_TPB 1024
#define STILE 16384             // edges per k_scat tile (64 KB stage)
#define EPT 16                  // edges per thread in k_scat (STILE/SCAT_TPB)
#define SORT_TPB 1024
#define CAP 18432               // bucket segment capacity (mean 16384, +16 sigma)

typedef _Float16 half8 __attribute__((ext_vector_type(8)));
typedef _Float16 half2v __attribute__((ext_vector_type(2)));

// ---------------- init: gpos[b] = b*CAP, gsum = 0 ----------------
__global__ void k_init(int* __restrict__ gpos, float* __restrict__ gsum,
                       int nbuck, int gsum_len) {
  int i = blockIdx.x * blockDim.x + threadIdx.x;
  if (i < nbuck) gpos[i] = i * CAP;
  if (i < gsum_len) gsum[i] = 0.0f;
}

// ---------------- tile-sort scatter into segmented buckets ----------------
__global__ void __launch_bounds__(SCAT_TPB)
k_scat(const int* __restrict__ src, const int* __restrict__ dst,
       int* __restrict__ gpos, unsigned* __restrict__ bucketed,
       int E, int nbuck) {
  __shared__ unsigned stage[STILE];   // 64 KB, bucket-sorted tile
  __shared__ int cnt[512];
  __shared__ int runp[512];
  __shared__ int lofs[513];
  __shared__ int base[512];
  __shared__ int wsum[16];
  int t = threadIdx.x;
  int ts = blockIdx.x * STILE;
  int count = min(STILE, E - ts);
  int d[EPT], s[EPT];

  for (int i = t; i < nbuck; i += SCAT_TPB) cnt[i] = 0;
  __syncthreads();
  // pass A: load tile into registers + count
#pragma unroll
  for (int j = 0; j < EPT; ++j) {
    int i = j * SCAT_TPB + t;
    if (i < count) {
      d[j] = dst[ts + i];
      s[j] = src[ts + i];
      atomicAdd(&cnt[d[j] >> BSH], 1);
    }
  }
  __syncthreads();
  // scan + global reservation (one atomic per non-empty bucket)
  {
    int v = (t < nbuck) ? cnt[t] : 0;
    int lane = t & 63, wid = t >> 6;
    int inc = v;
    for (int dd = 1; dd < 64; dd <<= 1) {
      int u = __shfl_up(inc, dd, 64);
      if (lane >= dd) inc += u;
    }
    if (lane == 63) wsum[wid] = inc;
    __syncthreads();
    int woff = 0;
    for (int w = 0; w < wid; ++w) woff += wsum[w];
    int excl = woff + inc - v;
    if (t < nbuck) {
      lofs[t] = excl;
      runp[t] = excl;
      base[t] = v ? atomicAdd(&gpos[t], v) : 0;
    }
    if (t == 0) lofs[nbuck] = count;
  }
  __syncthreads();
  // pass B: place registers into stage (bucket-sorted)
#pragma unroll
  for (int j = 0; j < EPT; ++j) {
    int i = j * SCAT_TPB + t;
    if (i < count) {
      int b = d[j] >> BSH;
      int p = atomicAdd(&runp[b], 1);
      stage[p] = ((unsigned)(d[j] & BMASK) << 18) | (unsigned)s[j];
    }
  }
  __syncthreads();
  // pass C: per-wave bucket-run copy (sequential stage reads / global writes)
  {
    int lane = t & 63, wid = t >> 6;
    for (int b = wid; b < nbuck; b += SCAT_TPB / 64) {
      int s0 = lofs[b], s1 = lofs[b + 1];
      int gb = base[b];
      for (int i = s0 + lane; i < s1; i += 64)
        bucketed[gb + (i - s0)] = stage[i];
    }
  }
}

// ---------------- per-bucket node sort: off/endo, dinv, full-bucket-staged csr ----------------
// 1 count pass + 1 scatter pass (whole bucket staged in 72 KB LDS).
__global__ void __launch_bounds__(SORT_TPB)
k_sortb(const unsigned* __restrict__ bucketed, const int* __restrict__ gpos,
        int* __restrict__ csr, int* __restrict__ off, int* __restrict__ endo,
        float* __restrict__ dinv, int N) {
  int b = blockIdx.x;
  int t = threadIdx.x;
  int n0 = b << BSH;
  int beg = b * CAP;
  int end = gpos[b];
  int total = end - beg;
  __shared__ int cntT[BNODES];
  __shared__ int run[BNODES];        // bucket-relative running positions
  __shared__ int wsum[16];
  __shared__ unsigned stage[CAP];    // 72 KB — whole bucket
  if (t < BNODES) cntT[t] = 0;
  __syncthreads();
  for (int i = beg + t; i < end; i += SORT_TPB) {
    unsigned p = bucketed[i];
    atomicAdd(&cntT[(p >> 18) & BMASK], 1);
  }
  __syncthreads();
  int v = (t < BNODES) ? cntT[t] : 0;
  int lane = t & 63, wid = t >> 6;
  int inc = v;
  for (int d = 1; d < 64; d <<= 1) {
    int u = __shfl_up(inc, d, 64);
    if (lane >= d) inc += u;
  }
  if (lane == 63) wsum[wid] = inc;
  __syncthreads();
  int woff = 0;
  for (int w = 0; w < wid; ++w) woff += wsum[w];
  int excl = woff + inc - v;
  if (t < BNODES) {
    run[t] = excl;
    int n = n0 + t;
    if (n < N) {
      off[n] = beg + excl;
      endo[n] = beg + excl + v;
      dinv[n] = rsqrtf((float)v + 1.0f);
    }
  }
  __syncthreads();
  // single scatter pass: place every edge's src into its node-grouped slot
  for (int i = beg + t; i < end; i += SORT_TPB) {
    unsigned p = bucketed[i];
    int idx = (p >> 18) & BMASK;
    int r = atomicAdd(&run[idx], 1);
    stage[r] = p & 0x3ffffu;
  }
  __syncthreads();
  // stream out coalesced
  for (int i = t; i < total; i += SORT_TPB)
    csr[beg + i] = (int)stage[i];
}

// ---------------- hs1 = fp16( dinv * (x @ W1) ) ----------------
// 1 thread/node, deep unrolled MLP (32 independent float4 x-loads), wave-uniform
// W1 pointer -> scalar s_loads. Two 8-lane restructures (r9/r10) were 6x SLOWER
// (latency-bound: 4-load MLP + lane-divergent W1); keep this structure.
__global__ void k_xw1(const float* __restrict__ x, const float* __restrict__ W1,
                      const float* __restrict__ dinv, _Float16* __restrict__ hs,
                      int n_nodes) {
  int n = blockIdx.x * blockDim.x + threadIdx.x;
  if (n >= n_nodes) return;
  const float4* xr = reinterpret_cast<const float4*>(x + (size_t)n * 128);
  float s[16];
#pragma unroll
  for (int c = 0; c < 16; ++c) s[c] = 0.0f;
#pragma unroll 4
  for (int k4 = 0; k4 < 32; ++k4) {
    float4 xv = xr[k4];
    const float* w = W1 + k4 * 64;  // uniform address -> scalar loads
#pragma unroll
    for (int c = 0; c < 16; ++c) s[c] = fmaf(xv.x, w[c], s[c]);
#pragma unroll
    for (int c = 0; c < 16; ++c) s[c] = fmaf(xv.y, w[16 + c], s[c]);
#pragma unroll
    for (int c = 0; c < 16; ++c) s[c] = fmaf(xv.z, w[32 + c], s[c]);
#pragma unroll
    for (int c = 0; c < 16; ++c) s[c] = fmaf(xv.w, w[48 + c], s[c]);
  }
  float dn = dinv[n];
  half8 v0, v1;
#pragma unroll
  for (int j = 0; j < 8; ++j) v0[j] = (_Float16)(dn * s[j]);
#pragma unroll
  for (int j = 0; j < 8; ++j) v1[j] = (_Float16)(dn * s[8 + j]);
  half8* hp = reinterpret_cast<half8*>(hs + (size_t)n * 16);
  hp[0] = v0;
  hp[1] = v1;
}

// ---------------- 8-lane gather: deep-batched, index-prefetched ----------------
__device__ __forceinline__ void gather2(const _Float16* __restrict__ tab,
                                        const int* __restrict__ csr,
                                        int beg, int end, int c2,
                                        float& a0, float& a1) {
  int i = beg;
  int n16 = (end - beg) >> 4;
  if (n16 > 0) {
    int idx[16];
#pragma unroll
    for (int j = 0; j < 16; ++j) idx[j] = csr[i + j];
    for (int it = 1; it < n16; ++it) {
      half2v f[16];
#pragma unroll
      for (int j = 0; j < 16; ++j)
        f[j] = *reinterpret_cast<const half2v*>(tab + (size_t)idx[j] * 16 + c2 * 2);
      // prefetch next batch of indices while table loads are in flight
#pragma unroll
      for (int j = 0; j < 16; ++j) idx[j] = csr[i + 16 + j];
#pragma unroll
      for (int j = 0; j < 16; ++j) { a0 += (float)f[j][0]; a1 += (float)f[j][1]; }
      i += 16;
    }
    // drain the last prefetched batch
    half2v f[16];
#pragma unroll
    for (int j = 0; j < 16; ++j)
      f[j] = *reinterpret_cast<const half2v*>(tab + (size_t)idx[j] * 16 + c2 * 2);
#pragma unroll
    for (int j = 0; j < 16; ++j) { a0 += (float)f[j][0]; a1 += (float)f[j][1]; }
    i += 16;
  }
  if (i + 8 <= end) {
    int idx8[8];
    half2v f[8];
#pragma unroll
    for (int j = 0; j < 8; ++j) idx8[j] = csr[i + j];
#pragma unroll
    for (int j = 0; j < 8; ++j)
      f[j] = *reinterpret_cast<const half2v*>(tab + (size_t)idx8[j] * 16 + c2 * 2);
#pragma unroll
    for (int j = 0; j < 8; ++j) { a0 += (float)f[j][0]; a1 += (float)f[j][1]; }
    i += 8;
  }
  for (; i < end; ++i) {
    int idx = csr[i];
    half2v f = *reinterpret_cast<const half2v*>(tab + (size_t)idx * 16 + c2 * 2);
    a0 += (float)f[0];
    a1 += (float)f[1];
  }
}

// ---------------- gather conv1 + relu + W2 transform (8 lanes/node) ----------------
__global__ void k_gc1(const _Float16* __restrict__ hs1, const int* __restrict__ off,
                      const int* __restrict__ endo, const int* __restrict__ csr,
                      const float* __restrict__ dinv, const float* __restrict__ b1,
                      const float* __restrict__ W2, _Float16* __restrict__ hs2, int N) {
  int t = blockIdx.x * blockDim.x + threadIdx.x;
  int n = t >> 3, c2 = t & 7;
  if (n >= N) return;
  half2v selfr = *reinterpret_cast<const half2v*>(hs1 + (size_t)n * 16 + c2 * 2);
  float a0 = (float)selfr[0], a1 = (float)selfr[1];
  gather2(hs1, csr, off[n], endo[n], c2, a0, a1);
  float dn = dinv[n];
  float h1a = fmaxf(fmaf(dn, a0, b1[c2 * 2 + 0]), 0.0f);
  float h1b = fmaxf(fmaf(dn, a1, b1[c2 * 2 + 1]), 0.0f);
  float oa = 0.0f, ob = 0.0f;
#pragma unroll
  for (int j = 0; j < 8; ++j) {
    float hk0 = __shfl(h1a, j, 8);  // h1[2j]
    float hk1 = __shfl(h1b, j, 8);  // h1[2j+1]
    oa = fmaf(hk0, W2[(2 * j) * 16 + c2 * 2 + 0], oa);
    ob = fmaf(hk0, W2[(2 * j) * 16 + c2 * 2 + 1], ob);
    oa = fmaf(hk1, W2[(2 * j + 1) * 16 + c2 * 2 + 0], oa);
    ob = fmaf(hk1, W2[(2 * j + 1) * 16 + c2 * 2 + 1], ob);
  }
  half2v outv;
  outv[0] = (_Float16)(dn * oa);
  outv[1] = (_Float16)(dn * ob);
  *reinterpret_cast<half2v*>(hs2 + (size_t)n * 16 + c2 * 2) = outv;
}

// ---------------- gather conv2 + bias + pool accumulate (8 lanes/node) ----------------
__global__ void k_gc2(const _Float16* __restrict__ hs2, const int* __restrict__ off,
                      const int* __restrict__ endo, const int* __restrict__ csr,
                      const float* __restrict__ dinv, const float* __restrict__ b2,
                      const int* __restrict__ batch, float* __restrict__ gsum, int N) {
  int t = threadIdx.x;
  int n = blockIdx.x * 32 + (t >> 3);
  int c2 = t & 7;
  float v0 = 0.0f, v1 = 0.0f;
  int g = 0;
  if (n < N) {
    half2v selfr = *reinterpret_cast<const half2v*>(hs2 + (size_t)n * 16 + c2 * 2);
    float a0 = (float)selfr[0], a1 = (float)selfr[1];
    gather2(hs2, csr, off[n], endo[n], c2, a0, a1);
    float dn = dinv[n];
    v0 = fmaf(dn, a0, b2[c2 * 2 + 0]);
    v1 = fmaf(dn, a1, b2[c2 * 2 + 1]);
    g = batch[n];
  }
  // block covers 32 consecutive nodes; batch is sorted -> usually one graph
  __shared__ float2 red[256];
  __shared__ int sg[2];
  int nfirst = blockIdx.x * 32;
  int nlast = min(nfirst + 31, N - 1);
  if (t == 0) sg[0] = batch[nfirst];
  if (t == 255) sg[1] = batch[nlast];
  __syncthreads();
  bool uniform = (sg[0] == sg[1]);
  if (uniform) {
    red[t] = make_float2(v0, v1);
    __syncthreads();
#pragma unroll
    for (int s2 = 16; s2 > 0; s2 >>= 1) {
      if ((t >> 3) < s2) {
        float2 a = red[t], b = red[t + s2 * 8];
        red[t] = make_float2(a.x + b.x, a.y + b.y);
      }
      __syncthreads();
    }
    if (t < 8) {
      float2 r = red[t];
      unsafeAtomicAdd(&gsum[(size_t)sg[0] * 16 + t * 2 + 0], r.x);
      unsafeAtomicAdd(&gsum[(size_t)sg[0] * 16 + t * 2 + 1], r.y);
    }
  } else if (n < N) {
    unsafeAtomicAdd(&gsum[(size_t)g * 16 + c2 * 2 + 0], v0);
    unsafeAtomicAdd(&gsum[(size_t)g * 16 + c2 * 2 + 1], v1);
  }
}

// ---------------- mean + FC head ----------------
__device__ __forceinline__ int lbound(const int* a, int n, int key) {
  int lo = 0, hi = n;
  while (lo < hi) {
    int mid = (lo + hi) >> 1;
    if (a[mid] < key) lo = mid + 1; else hi = mid;
  }
  return lo;
}

__global__ void k_final(const float* __restrict__ gsum, const int* __restrict__ batch,
                        const float* __restrict__ fcW, const float* __restrict__ fcb,
                        float* __restrict__ out, int n_nodes, int num_graphs) {
  int g = blockIdx.x * blockDim.x + threadIdx.x;
  if (g >= num_graphs) return;
  int lo = lbound(batch, n_nodes, g);
  int hi = lbound(batch, n_nodes, g + 1);
  float cnt = (float)(hi - lo);
  float inv = 1.0f / fmaxf(cnt, 1.0f);
  float gv[16];
#pragma unroll
  for (int c = 0; c < 16; ++c) gv[c] = gsum[(size_t)g * 16 + c] * inv;
  float o[16];
#pragma unroll
  for (int c = 0; c < 16; ++c) o[c] = fcb[c];
#pragma unroll
  for (int k = 0; k < 16; ++k) {
    float gk = gv[k];
    const float* w = fcW + k * 16;
#pragma unroll
    for (int c = 0; c < 16; ++c) o[c] = fmaf(gk, w[c], o[c]);
  }
#pragma unroll
  for (int c = 0; c < 16; ++c) out[(size_t)g * 16 + c] = o[c];
}

extern "C" void kernel_launch(void* const* d_in, const int* in_sizes, int n_in,
                              void* d_out, int out_size, void* d_ws, size_t ws_size,
                              hipStream_t stream) {
  const float* x   = (const float*)d_in[0];
  const float* W1  = (const float*)d_in[1];
  const float* b1  = (const float*)d_in[2];
  const float* W2  = (const float*)d_in[3];
  const float* b2  = (const float*)d_in[4];
  const float* fcW = (const float*)d_in[5];
  const float* fcb = (const float*)d_in[6];
  const int* ei    = (const int*)d_in[7];
  const int* batch = (const int*)d_in[8];

  const int IN_CH = 128, HID = 16, NCLS = 16;
  int n_nodes = in_sizes[0] / IN_CH;       // 200000
  int E = in_sizes[7] / 2;                 // 6400000
  int num_graphs = out_size / NCLS;        // 512
  const int* src = ei;
  const int* dst = ei + E;
  int nbuck = (n_nodes + BNODES - 1) >> BSH;  // 391 (<= 512 assumed)
  size_t seg_elems = (size_t)nbuck * CAP;     // segmented capacity

  // workspace: region aliases {bucketed} then {H1, H2}; csr separate.
  char* ws = (char*)d_ws;
  size_t h_bytes = sizeof(_Float16) * (size_t)n_nodes * 16;  // 6.4 MB each
  size_t region_bytes = 2 * h_bytes;
  if (sizeof(unsigned) * seg_elems > region_bytes)
    region_bytes = sizeof(unsigned) * seg_elems;
  unsigned* bucketed = (unsigned*)ws;
  _Float16* H1  = (_Float16*)ws;
  _Float16* H2  = (_Float16*)(ws + h_bytes);
  ws += region_bytes;
  int*   csr  = (int*)ws;   ws += sizeof(int) * seg_elems;
  int*   off  = (int*)ws;   ws += sizeof(int) * ((size_t)n_nodes + 64);
  int*   endo = (int*)ws;   ws += sizeof(int) * ((size_t)n_nodes + 64);
  float* dinv = (float*)ws; ws += sizeof(float) * (size_t)n_nodes;
  int*   gpos = (int*)ws;   ws += sizeof(int) * 1056;
  float* gsum = (float*)ws;

  int gn  = (n_nodes + TPB - 1) / TPB;
  int gg  = (num_graphs + TPB - 1) / TPB;
  int gnc = ((n_nodes * 8) + TPB - 1) / TPB;   // gather conv1: 8 lanes/node
  int gb  = (n_nodes + 31) / 32;               // k_gc2: 32 nodes/block
  int gs  = (E + STILE - 1) / STILE;           // tiles for k_scat
  int gi  = ((nbuck > num_graphs * HID ? nbuck : num_graphs * HID) + TPB - 1) / TPB;

  k_init <<<gi, TPB, 0, stream>>>(gpos, gsum, nbuck, num_graphs * HID);
  k_scat <<<gs, SCAT_TPB, 0, stream>>>(src, dst, gpos, bucketed, E, nbuck);
  k_sortb<<<nbuck, SORT_TPB, 0, stream>>>(bucketed, gpos, csr, off, endo,
                                          dinv, n_nodes);
  k_xw1  <<<gn, TPB, 0, stream>>>(x, W1, dinv, H1, n_nodes);
  k_gc1  <<<gnc, TPB, 0, stream>>>(H1, off, endo, csr, dinv, b1, W2, H2, n_nodes);
  k_gc2  <<<gb, TPB, 0, stream>>>(H2, off, endo, csr, dinv, b2, batch, gsum, n_nodes);
  k_final<<<gg, TPB, 0, stream>>>(gsum, batch, fcW, fcb, (float*)d_out,
                                  n_nodes, num_graphs);
}